// Round 21
// baseline (118.536 us; speedup 1.0000x reference)
//
#include <hip/hip_runtime.h>
#include <hip/hip_bf16.h>
#include <stdint.h>

// KipfMLPGNN: B=32, N=64, D=128, H=256, L=3.
// v21 = v20 with the staging-traffic bottleneck removed (R20 PMC: FETCH 38MB
// / 773 GB/s = the whole 50us dispatch):
//  - k_esum materializes E' once per layer as fp16 (0.5MB, L2-resident
//    everywhere); k_fused blocks read 12KB instead of 98KB (5-way Sp re-read
//    amplification gone).
//  - T-GEMM A-frags read DIRECTLY from global E16 (L2-hit, same pattern as
//    W1 frag loads) -> no Els LDS stage, no first barrier, LDS 32->20KB.
// Grid (8 rg, 32 b, 4 z=p*2+ch) = 1024 blocks; c-sum partials to slice
// p*2+ch, folded by next k_esum / k_out.

#define NB 32
#define NN 64
#define DD 128
#define HH 256

typedef __attribute__((ext_vector_type(4))) float f32x4;
typedef __attribute__((ext_vector_type(8))) _Float16 f16x8;

__device__ __forceinline__ uint64_t cvt4h(f32x4 v) {
  union { _Float16 h[4]; uint64_t u; } x;
  x.h[0] = (_Float16)v[0]; x.h[1] = (_Float16)v[1];
  x.h[2] = (_Float16)v[2]; x.h[3] = (_Float16)v[3];
  return x.u;
}

// Fused setup: gather E0 (256 blk) | W1/W2 -> fp16 (192 blk)
__global__ __launch_bounds__(256) void k_setup(const int* __restrict__ x,
                                               const float* __restrict__ table,
                                               float* __restrict__ E0,
                                               const float* __restrict__ W1_0,
                                               const float* __restrict__ W1_1,
                                               const float* __restrict__ W2_0,
                                               const float* __restrict__ W2_1,
                                               _Float16* __restrict__ W1fp,
                                               _Float16* __restrict__ W2fp) {
  int bid = blockIdx.x, t = threadIdx.x;
  if (bid < 256) {
    int i = bid * 256 + t;
    int node = i >> 5;
    ((f32x4*)E0)[i] = ((const f32x4*)table)[(size_t)x[node] * 32 + (i & 31)];
  } else {
    int tid = (bid - 256) * 256 + t;     // 49152 f32x4 chunks
    const float* src; uint64_t* dst; int off;
    if (tid < 32768) {
      src = (tid < 16384) ? W1_0 : W1_1;
      off = tid & 16383;
      dst = (uint64_t*)W1fp + (tid >> 14) * 16384 + off;
    } else {
      int t2 = tid - 32768;
      src = (t2 < 8192) ? W2_0 : W2_1;
      off = t2 & 8191;
      dst = (uint64_t*)W2fp + (t2 >> 13) * 8192 + off;
    }
    *dst = cvt4h(((const f32x4*)src)[off]);
  }
}

// E16[node][128] f16 = E0 [+ Sum_s spA[s]] [+ Sum_s spB[s]]   (65536 chunks)
template <int NSP>
__global__ __launch_bounds__(256) void k_esum(const float* __restrict__ E0,
                                              const float* __restrict__ spA,
                                              const float* __restrict__ spB,
                                              _Float16* __restrict__ E16) {
  int i = blockIdx.x * 256 + threadIdx.x;
  f32x4 v = ((const f32x4*)E0)[i];
  if (NSP >= 1) {
#pragma unroll
    for (int s = 0; s < 4; ++s) v += ((const f32x4*)spA)[s * 65536 + i];
  }
  if (NSP >= 2) {
#pragma unroll
    for (int s = 0; s < 4; ++s) v += ((const f32x4*)spB)[s * 65536 + i];
  }
  ((uint64_t*)E16)[i] = cvt4h(v);
}

// k_fused<NR>: grid (8 or 1, 32, 4) = (rg, b, z=p*2+ch). 256 thr / 4 waves.
// T-GEMM A-frags from global E16 (L2-hit); Ts/Tr -> LDS; edge loop.
template <int NR>
__global__ __launch_bounds__(256) void k_fused(
    const _Float16* __restrict__ E16,
    float* __restrict__ spOut,
    const _Float16* __restrict__ W1fp,
    const _Float16* __restrict__ W2fp,
    const float* __restrict__ b1_0, const float* __restrict__ b1_1,
    const float* __restrict__ b2_0, const float* __restrict__ b2_1,
    const int* __restrict__ arcs) {
  __shared__ char lds[20480];
  char* Tsl = lds;              // [32 c][512 B] Ts f16, swizzled
  char* Trl = lds + 16384;      // [8 r][512 B]  Tr f16 (+b1), swizzled

  int t = threadIdx.x;
  int rg = blockIdx.x, b = blockIdx.y;
  int p = blockIdx.z >> 1, ch = blockIdx.z & 1;
  int rbase = rg * NR;
  int lane = t & 63, w = t >> 6, col = lane & 15, khi = lane >> 4;
  const f32x4 z4 = {0.f, 0.f, 0.f, 0.f};
  const _Float16* Eb = E16 + (size_t)b * NN * DD;

  // ---- phase 1: T-GEMM. Wave w owns h-slice [w*64, w*64+64) ----
  const _Float16* Wq = W1fp + p * 65536;     // [256 h][256 in]
  const float* b1p = p ? b1_1 : b1_0;

#pragma unroll
  for (int nth = 0; nth < 2; ++nth) {        // Ts: 32 c x 32 h per pass
    f16x8 bfr[2][4];
#pragma unroll
    for (int nt = 0; nt < 2; ++nt) {
      int h = w * 64 + nth * 32 + nt * 16 + col;
#pragma unroll
      for (int ks = 0; ks < 4; ++ks)
        bfr[nt][ks] = *(const f16x8*)(Wq + h * 256 + ks * 32 + khi * 8);
    }
    f32x4 tacc[2][2];
#pragma unroll
    for (int mt = 0; mt < 2; ++mt) { tacc[mt][0] = z4; tacc[mt][1] = z4; }
#pragma unroll
    for (int ks = 0; ks < 4; ++ks) {
      f16x8 a[2];
#pragma unroll
      for (int mt = 0; mt < 2; ++mt) {
        int node = ch * 32 + mt * 16 + col;
        a[mt] = *(const f16x8*)(Eb + node * DD + ks * 32 + khi * 8);
      }
#pragma unroll
      for (int mt = 0; mt < 2; ++mt) {
        tacc[mt][0] = __builtin_amdgcn_mfma_f32_16x16x32_f16(a[mt], bfr[0][ks],
                                                             tacc[mt][0], 0, 0, 0);
        tacc[mt][1] = __builtin_amdgcn_mfma_f32_16x16x32_f16(a[mt], bfr[1][ks],
                                                             tacc[mt][1], 0, 0, 0);
      }
    }
#pragma unroll
    for (int mt = 0; mt < 2; ++mt)
#pragma unroll
      for (int nt = 0; nt < 2; ++nt) {
        int h = w * 64 + nth * 32 + nt * 16 + col;
#pragma unroll
        for (int j = 0; j < 4; ++j) {
          int c = mt * 16 + khi * 4 + j;
          *(_Float16*)(Tsl + c * 512 + ((h * 2) ^ ((c & 7) << 4))) =
              (_Float16)tacc[mt][nt][j];
        }
      }
  }
#pragma unroll
  for (int nth = 0; nth < 2; ++nth) {        // Tr: rows rbase.. (keep 8)
    f16x8 bfrR[2][4];
#pragma unroll
    for (int nt = 0; nt < 2; ++nt) {
      int h = w * 64 + nth * 32 + nt * 16 + col;
#pragma unroll
      for (int ks = 0; ks < 4; ++ks)
        bfrR[nt][ks] = *(const f16x8*)(Wq + h * 256 + 128 + ks * 32 + khi * 8);
    }
    f32x4 taccR[2] = {z4, z4};
#pragma unroll
    for (int ks = 0; ks < 4; ++ks) {
      int node = rbase + col; if (node > 63) node = 63;
      f16x8 ar = *(const f16x8*)(Eb + node * DD + ks * 32 + khi * 8);
      taccR[0] = __builtin_amdgcn_mfma_f32_16x16x32_f16(ar, bfrR[0][ks],
                                                        taccR[0], 0, 0, 0);
      taccR[1] = __builtin_amdgcn_mfma_f32_16x16x32_f16(ar, bfrR[1][ks],
                                                        taccR[1], 0, 0, 0);
    }
    if (khi < 2) {                           // rows 0..7 valid
#pragma unroll
      for (int nt = 0; nt < 2; ++nt) {
        int h = w * 64 + nth * 32 + nt * 16 + col;
        float bb = b1p[h];
#pragma unroll
        for (int j = 0; j < 4; ++j) {
          int lr = khi * 4 + j;
          *(_Float16*)(Trl + lr * 512 + ((h * 2) ^ ((lr & 7) << 4))) =
              (_Float16)(taccR[nt][j] + bb);
        }
      }
    }
  }
  __syncthreads();

  // ---- phase 2: edge loop over NR r's; wave w owns d [w*32, w*32+32) ----
  int d0 = w * 32 + col;
  const _Float16* W2p = W2fp + p * 32768;
  f16x8 bv[2][8];
#pragma unroll
  for (int nt = 0; nt < 2; ++nt)
#pragma unroll
    for (int ks = 0; ks < 8; ++ks)
      bv[nt][ks] = *(const f16x8*)(W2p + (d0 + nt * 16) * 256 + ks * 32 + khi * 8);
  const float* b2p = p ? b2_1 : b2_0;
  float b2v[2] = {b2p[d0], b2p[d0 + 16]};

#pragma unroll 1
  for (int r = 0; r < NR; ++r) {
    f32x4 acc[2][2];
#pragma unroll
    for (int mt = 0; mt < 2; ++mt) { acc[mt][0] = z4; acc[mt][1] = z4; }
#pragma unroll
    for (int ks = 0; ks < 8; ++ks) {
      f16x8 trv = *(const f16x8*)(Trl + r * 512 +
                                  ((ks * 64 + khi * 16) ^ ((r & 7) << 4)));
#pragma unroll
      for (int mt = 0; mt < 2; ++mt) {
        int c = mt * 16 + col;
        f16x8 ts = *(const f16x8*)(Tsl + c * 512 +
                                   ((ks * 64 + khi * 16) ^ ((c & 7) << 4)));
        f16x8 zv = {};
        f16x8 a = __builtin_elementwise_max(ts + trv, zv);
        acc[mt][0] = __builtin_amdgcn_mfma_f32_16x16x32_f16(a, bv[0][ks],
                                                            acc[mt][0], 0, 0, 0);
        acc[mt][1] = __builtin_amdgcn_mfma_f32_16x16x32_f16(a, bv[1][ks],
                                                            acc[mt][1], 0, 0, 0);
      }
    }
    int rr = rbase + r;
    const int* arow = arcs + ((size_t)(b * NN + rr)) * NN + ch * 32;
    float s0 = 0.f, s1 = 0.f;
#pragma unroll
    for (int mt = 0; mt < 2; ++mt) {
      const int4 av = *(const int4*)(arow + mt * 16 + khi * 4);
#pragma unroll
      for (int j = 0; j < 4; ++j) {
        int ai = (j == 0) ? av.x : (j == 1) ? av.y : (j == 2) ? av.z : av.w;
        float wgt = p ? (float)ai : 1.0f - (float)ai;
        s0 = fmaf(wgt, fmaxf(acc[mt][0][j] + b2v[0], 0.f), s0);
        s1 = fmaf(wgt, fmaxf(acc[mt][1][j] + b2v[1], 0.f), s1);
      }
    }
    s0 += __shfl_xor(s0, 16); s0 += __shfl_xor(s0, 32);
    s1 += __shfl_xor(s1, 16); s1 += __shfl_xor(s1, 32);
    if (khi == 0) {
      int slice = p * 2 + ch;
      float* o = (NR == 1)
          ? spOut + (size_t)(slice * NB + b) * DD
          : spOut + ((size_t)(slice * NB + b) * NN + rr) * DD;
      o[d0] = s0; o[d0 + 16] = s1;
    }
  }
}

// out[b][d] = E0[b][0][d] + Sum_s SpA[s][b][0][d] + SpB[s][b][0][d] + SpC[s][b][d]
__global__ __launch_bounds__(256) void k_out(const float* __restrict__ E0,
                                             const float* __restrict__ spA,
                                             const float* __restrict__ spB,
                                             const float* __restrict__ spC,
                                             float* __restrict__ out) {
  int i = blockIdx.x * 256 + threadIdx.x;      // 4096
  int b = i >> 7, d = i & 127;
  float acc = E0[(size_t)b * NN * DD + d];
#pragma unroll
  for (int s = 0; s < 4; ++s) {
    acc += spA[(size_t)(s * NB + b) * NN * DD + d];
    acc += spB[(size_t)(s * NB + b) * NN * DD + d];
    acc += spC[(size_t)(s * NB + b) * DD + d];
  }
  out[i] = acc;
}

extern "C" void kernel_launch(void* const* d_in, const int* in_sizes, int n_in,
                              void* d_out, int out_size, void* d_ws, size_t ws_size,
                              hipStream_t stream) {
  const int* x       = (const int*)d_in[0];
  const int* arcs    = (const int*)d_in[1];
  const float* table = (const float*)d_in[3];
  const float* W1_0  = (const float*)d_in[4];
  const float* b1_0  = (const float*)d_in[5];
  const float* W2_0  = (const float*)d_in[6];
  const float* b2_0  = (const float*)d_in[7];
  const float* W1_1  = (const float*)d_in[8];
  const float* b1_1  = (const float*)d_in[9];
  const float* W2_1  = (const float*)d_in[10];
  const float* b2_1  = (const float*)d_in[11];
  float* out = (float*)d_out;

  char* ws = (char*)d_ws;
  float* E0        = (float*)ws;                                   // 1 MB
  _Float16* W1fp   = (_Float16*)(ws + (1u << 20));                 // 256 KB
  _Float16* W2fp   = (_Float16*)(ws + (1u << 20) + (256u << 10));  // 128 KB
  _Float16* E16    = (_Float16*)(ws + (1u << 20) + (384u << 10));  // 512 KB
  float* SpA       = (float*)(ws + (2u << 20));                    // 4 MB
  float* SpB       = (float*)(ws + (6u << 20));                    // 4 MB
  float* SpC       = (float*)(ws + (10u << 20));                   // 64 KB

  k_setup<<<448, 256, 0, stream>>>(x, table, E0, W1_0, W1_1, W2_0, W2_1,
                                   W1fp, W2fp);
  k_esum<0><<<256, 256, 0, stream>>>(E0, E0, E0, E16);
  k_fused<8><<<dim3(8, 32, 4), 256, 0, stream>>>(
      E16, SpA, W1fp, W2fp, b1_0, b1_1, b2_0, b2_1, arcs);
  k_esum<1><<<256, 256, 0, stream>>>(E0, SpA, E0, E16);
  k_fused<8><<<dim3(8, 32, 4), 256, 0, stream>>>(
      E16, SpB, W1fp, W2fp, b1_0, b1_1, b2_0, b2_1, arcs);
  k_esum<2><<<256, 256, 0, stream>>>(E0, SpA, SpB, E16);
  k_fused<1><<<dim3(1, 32, 4), 256, 0, stream>>>(
      E16, SpC, W1fp, W2fp, b1_0, b1_1, b2_0, b2_1, arcs);
  k_out<<<16, 256, 0, stream>>>(E0, SpA, SpB, SpC, out);
}

// Round 22
// 114.650 us; speedup vs baseline: 1.0339x; 1.0339x over previous
//
#include <hip/hip_runtime.h>
#include <hip/hip_bf16.h>
#include <stdint.h>

// KipfMLPGNN: B=32, N=64, D=128, H=256, L=3.
// v24 = v16 (champion, 102us) + residency/pipelining levers:
//  - E16: E' materialized once per layer as fp16 by k_esum (0.5MB,
//    L2-resident); k_fused T-GEMM A-frags read E16 directly from global ->
//    no Els LDS stage -> LDS 53->36KB -> 4 blocks/CU (was 2).
//  - edge r-loop "#pragma unroll 2": scheduler hoists r+1 LDS loads under
//    r's MFMA burst.
// Corrected cost model (R21): per k_fused<8>: MFMA-busy floor ~10us,
// LDS ~15us, VALU ~7-15us; wall = overlap at low effective waves/SIMD.

#define NB 32
#define NN 64
#define DD 128
#define HH 256

typedef __attribute__((ext_vector_type(4))) float f32x4;
typedef __attribute__((ext_vector_type(8))) _Float16 f16x8;

__device__ __forceinline__ uint64_t cvt4h(f32x4 v) {
  union { _Float16 h[4]; uint64_t u; } x;
  x.h[0] = (_Float16)v[0]; x.h[1] = (_Float16)v[1];
  x.h[2] = (_Float16)v[2]; x.h[3] = (_Float16)v[3];
  return x.u;
}

// Fused setup: gather E0 (256 blk) | W1/W2 -> fp16 (192 blk)
__global__ __launch_bounds__(256) void k_setup(const int* __restrict__ x,
                                               const float* __restrict__ table,
                                               float* __restrict__ E0,
                                               const float* __restrict__ W1_0,
                                               const float* __restrict__ W1_1,
                                               const float* __restrict__ W2_0,
                                               const float* __restrict__ W2_1,
                                               _Float16* __restrict__ W1fp,
                                               _Float16* __restrict__ W2fp) {
  int bid = blockIdx.x, t = threadIdx.x;
  if (bid < 256) {
    int i = bid * 256 + t;
    int node = i >> 5;
    ((f32x4*)E0)[i] = ((const f32x4*)table)[(size_t)x[node] * 32 + (i & 31)];
  } else {
    int tid = (bid - 256) * 256 + t;     // 49152 f32x4 chunks
    const float* src; uint64_t* dst; int off;
    if (tid < 32768) {
      src = (tid < 16384) ? W1_0 : W1_1;
      off = tid & 16383;
      dst = (uint64_t*)W1fp + (tid >> 14) * 16384 + off;
    } else {
      int t2 = tid - 32768;
      src = (t2 < 8192) ? W2_0 : W2_1;
      off = t2 & 8191;
      dst = (uint64_t*)W2fp + (t2 >> 13) * 8192 + off;
    }
    *dst = cvt4h(((const f32x4*)src)[off]);
  }
}

// E16[node][128] f16 = E0 [+ spA slices] [+ spB slices]   (65536 chunks)
template <int NSP>
__global__ __launch_bounds__(256) void k_esum(const float* __restrict__ E0,
                                              const float* __restrict__ spA,
                                              const float* __restrict__ spB,
                                              _Float16* __restrict__ E16) {
  int i = blockIdx.x * 256 + threadIdx.x;
  f32x4 v = ((const f32x4*)E0)[i];
  if (NSP >= 1) {
#pragma unroll
    for (int s = 0; s < 2; ++s) v += ((const f32x4*)spA)[s * 65536 + i];
  }
  if (NSP >= 2) {
#pragma unroll
    for (int s = 0; s < 2; ++s) v += ((const f32x4*)spB)[s * 65536 + i];
  }
  ((uint64_t*)E16)[i] = cvt4h(v);
}

// k_fused<NR>: grid (NR==8 ? 8 : 1, 32, 2) = (rg, b, p). 256 thr / 4 waves.
template <int NR>
__global__ __launch_bounds__(256) void k_fused(
    const _Float16* __restrict__ E16,
    float* __restrict__ spOut,
    const _Float16* __restrict__ W1fp,
    const _Float16* __restrict__ W2fp,
    const float* __restrict__ b1_0, const float* __restrict__ b1_1,
    const float* __restrict__ b2_0, const float* __restrict__ b2_1,
    const int* __restrict__ arcs) {
  __shared__ char lds[36864];
  char* Tsl = lds;            // [64 c][512 B]  Ts f16, swizzled
  char* Trl = lds + 32768;    // [8 r][512 B]   Tr f16 (+b1), swizzled

  int t = threadIdx.x;
  int rg = blockIdx.x, b = blockIdx.y, p = blockIdx.z;
  int rbase = rg * NR;
  int lane = t & 63, w = t >> 6, col = lane & 15, khi = lane >> 4;
  const f32x4 z4 = {0.f, 0.f, 0.f, 0.f};
  const _Float16* Eb = E16 + (size_t)b * NN * DD;

  // ---- phase 1: T-GEMM (A-frags direct from global E16, L2-hit) ----
  const _Float16* Wq = W1fp + p * 65536;     // [256 h][256 in]
  const float* b1p = p ? b1_1 : b1_0;

#pragma unroll
  for (int nth = 0; nth < 2; ++nth) {        // Ts: 64 c x 32 h per pass
    f16x8 bfr[2][4];
#pragma unroll
    for (int nt = 0; nt < 2; ++nt) {
      int h = w * 64 + nth * 32 + nt * 16 + col;
#pragma unroll
      for (int ks = 0; ks < 4; ++ks)
        bfr[nt][ks] = *(const f16x8*)(Wq + h * 256 + ks * 32 + khi * 8);
    }
    f32x4 tacc[4][2];
#pragma unroll
    for (int mt = 0; mt < 4; ++mt) { tacc[mt][0] = z4; tacc[mt][1] = z4; }
#pragma unroll
    for (int ks = 0; ks < 4; ++ks) {
      f16x8 a[4];
#pragma unroll
      for (int mt = 0; mt < 4; ++mt) {
        int node = mt * 16 + col;
        a[mt] = *(const f16x8*)(Eb + node * DD + ks * 32 + khi * 8);
      }
#pragma unroll
      for (int mt = 0; mt < 4; ++mt) {
        tacc[mt][0] = __builtin_amdgcn_mfma_f32_16x16x32_f16(a[mt], bfr[0][ks],
                                                             tacc[mt][0], 0, 0, 0);
        tacc[mt][1] = __builtin_amdgcn_mfma_f32_16x16x32_f16(a[mt], bfr[1][ks],
                                                             tacc[mt][1], 0, 0, 0);
      }
    }
#pragma unroll
    for (int mt = 0; mt < 4; ++mt)
#pragma unroll
      for (int nt = 0; nt < 2; ++nt) {
        int h = w * 64 + nth * 32 + nt * 16 + col;
#pragma unroll
        for (int j = 0; j < 4; ++j) {
          int c = mt * 16 + khi * 4 + j;
          *(_Float16*)(Tsl + c * 512 + ((h * 2) ^ ((c & 7) << 4))) =
              (_Float16)tacc[mt][nt][j];
        }
      }
  }
  {  // Tr: one 16-node group; keep 8 rows selected by sel
    int mt_t = (NR == 1) ? 0 : (rg >> 1);
    int sel = (NR == 1) ? 0 : (rg & 1);
#pragma unroll
    for (int nth = 0; nth < 2; ++nth) {
      f16x8 bfr[2][4];
#pragma unroll
      for (int nt = 0; nt < 2; ++nt) {
        int h = w * 64 + nth * 32 + nt * 16 + col;
#pragma unroll
        for (int ks = 0; ks < 4; ++ks)
          bfr[nt][ks] = *(const f16x8*)(Wq + h * 256 + 128 + ks * 32 + khi * 8);
      }
      f32x4 tacc[2] = {z4, z4};
#pragma unroll
      for (int ks = 0; ks < 4; ++ks) {
        int node = mt_t * 16 + col;
        f16x8 a = *(const f16x8*)(Eb + node * DD + ks * 32 + khi * 8);
        tacc[0] = __builtin_amdgcn_mfma_f32_16x16x32_f16(a, bfr[0][ks], tacc[0], 0, 0, 0);
        tacc[1] = __builtin_amdgcn_mfma_f32_16x16x32_f16(a, bfr[1][ks], tacc[1], 0, 0, 0);
      }
      if ((khi >> 1) == sel) {
#pragma unroll
        for (int nt = 0; nt < 2; ++nt) {
          int h = w * 64 + nth * 32 + nt * 16 + col;
          float bb = b1p[h];
#pragma unroll
          for (int j = 0; j < 4; ++j) {
            int lr = (khi & 1) * 4 + j;
            *(_Float16*)(Trl + lr * 512 + ((h * 2) ^ ((lr & 7) << 4))) =
                (_Float16)(tacc[nt][j] + bb);
          }
        }
      }
    }
  }
  __syncthreads();

  // ---- phase 2: edge loop; wave w owns d [w*32, w*32+32) ----
  int d0 = w * 32 + col;
  const _Float16* W2p = W2fp + p * 32768;
  f16x8 bv[2][8];
#pragma unroll
  for (int nt = 0; nt < 2; ++nt)
#pragma unroll
    for (int ks = 0; ks < 8; ++ks)
      bv[nt][ks] = *(const f16x8*)(W2p + (d0 + nt * 16) * 256 + ks * 32 + khi * 8);
  const float* b2p = p ? b2_1 : b2_0;
  float b2v[2] = {b2p[d0], b2p[d0 + 16]};

#pragma unroll 2
  for (int r = 0; r < NR; ++r) {
    f32x4 acc[4][2];
#pragma unroll
    for (int mt = 0; mt < 4; ++mt) { acc[mt][0] = z4; acc[mt][1] = z4; }
#pragma unroll
    for (int ks = 0; ks < 8; ++ks) {
      f16x8 trv = *(const f16x8*)(Trl + r * 512 +
                                  ((ks * 64 + khi * 16) ^ ((r & 7) << 4)));
#pragma unroll
      for (int mt = 0; mt < 4; ++mt) {
        int c = mt * 16 + col;
        f16x8 ts = *(const f16x8*)(Tsl + c * 512 +
                                   ((ks * 64 + khi * 16) ^ ((c & 7) << 4)));
        f16x8 zv = {};
        f16x8 a = __builtin_elementwise_max(ts + trv, zv);
        acc[mt][0] = __builtin_amdgcn_mfma_f32_16x16x32_f16(a, bv[0][ks],
                                                            acc[mt][0], 0, 0, 0);
        acc[mt][1] = __builtin_amdgcn_mfma_f32_16x16x32_f16(a, bv[1][ks],
                                                            acc[mt][1], 0, 0, 0);
      }
    }
    int rr = rbase + r;
    const int* arow = arcs + ((size_t)(b * NN + rr)) * NN;
    float s0 = 0.f, s1 = 0.f;
#pragma unroll
    for (int mt = 0; mt < 4; ++mt) {
      const int4 av = *(const int4*)(arow + mt * 16 + khi * 4);
#pragma unroll
      for (int j = 0; j < 4; ++j) {
        int ai = (j == 0) ? av.x : (j == 1) ? av.y : (j == 2) ? av.z : av.w;
        float wgt = p ? (float)ai : 1.0f - (float)ai;
        s0 = fmaf(wgt, fmaxf(acc[mt][0][j] + b2v[0], 0.f), s0);
        s1 = fmaf(wgt, fmaxf(acc[mt][1][j] + b2v[1], 0.f), s1);
      }
    }
    s0 += __shfl_xor(s0, 16); s0 += __shfl_xor(s0, 32);
    s1 += __shfl_xor(s1, 16); s1 += __shfl_xor(s1, 32);
    if (khi == 0) {
      if (NR == 1) {
        float* o = spOut + (size_t)(p * NB + b) * DD;
        o[d0] = s0; o[d0 + 16] = s1;
      } else {
        float* o = spOut + ((size_t)(p * NB + b) * NN + rr) * DD;
        o[d0] = s0; o[d0 + 16] = s1;
      }
    }
  }
}

// out[b][d] = E0[b][0][d] + SpA[0..1][b][0][d] + SpB[0..1][b][0][d] + SpC[0..1][b][d]
__global__ __launch_bounds__(256) void k_out(const float* __restrict__ E0,
                                             const float* __restrict__ spA,
                                             const float* __restrict__ spB,
                                             const float* __restrict__ spC,
                                             float* __restrict__ out) {
  int i = blockIdx.x * 256 + threadIdx.x;      // 4096
  int b = i >> 7, d = i & 127;
  float acc = E0[(size_t)b * NN * DD + d];
  acc += spA[(size_t)b * NN * DD + d] + spA[(size_t)(NB + b) * NN * DD + d];
  acc += spB[(size_t)b * NN * DD + d] + spB[(size_t)(NB + b) * NN * DD + d];
  acc += spC[(size_t)b * DD + d] + spC[(size_t)(NB + b) * DD + d];
  out[i] = acc;
}

extern "C" void kernel_launch(void* const* d_in, const int* in_sizes, int n_in,
                              void* d_out, int out_size, void* d_ws, size_t ws_size,
                              hipStream_t stream) {
  const int* x       = (const int*)d_in[0];
  const int* arcs    = (const int*)d_in[1];
  const float* table = (const float*)d_in[3];
  const float* W1_0  = (const float*)d_in[4];
  const float* b1_0  = (const float*)d_in[5];
  const float* W2_0  = (const float*)d_in[6];
  const float* b2_0  = (const float*)d_in[7];
  const float* W1_1  = (const float*)d_in[8];
  const float* b1_1  = (const float*)d_in[9];
  const float* W2_1  = (const float*)d_in[10];
  const float* b2_1  = (const float*)d_in[11];
  float* out = (float*)d_out;

  char* ws = (char*)d_ws;
  float* E0        = (float*)ws;                                   // 1 MB
  _Float16* W1fp   = (_Float16*)(ws + (1u << 20));                 // 256 KB
  _Float16* W2fp   = (_Float16*)(ws + (1u << 20) + (256u << 10));  // 128 KB
  _Float16* E16    = (_Float16*)(ws + (1u << 20) + (384u << 10));  // 512 KB
  float* SpA       = (float*)(ws + (2u << 20));                    // 2 MB
  float* SpB       = (float*)(ws + (4u << 20));                    // 2 MB
  float* SpC       = (float*)(ws + (6u << 20));                    // 32 KB

  k_setup<<<448, 256, 0, stream>>>(x, table, E0, W1_0, W1_1, W2_0, W2_1,
                                   W1fp, W2fp);
  k_esum<0><<<256, 256, 0, stream>>>(E0, E0, E0, E16);
  k_fused<8><<<dim3(8, 32, 2), 256, 0, stream>>>(
      E16, SpA, W1fp, W2fp, b1_0, b1_1, b2_0, b2_1, arcs);
  k_esum<1><<<256, 256, 0, stream>>>(E0, SpA, E0, E16);
  k_fused<8><<<dim3(8, 32, 2), 256, 0, stream>>>(
      E16, SpB, W1fp, W2fp, b1_0, b1_1, b2_0, b2_1, arcs);
  k_esum<2><<<256, 256, 0, stream>>>(E0, SpA, SpB, E16);
  k_fused<1><<<dim3(1, 32, 2), 256, 0, stream>>>(
      E16, SpC, W1fp, W2fp, b1_0, b1_1, b2_0, b2_1, arcs);
  k_out<<<16, 256, 0, stream>>>(E0, SpA, SpB, SpC, out);
}

// Round 23
// 114.533 us; speedup vs baseline: 1.0350x; 1.0010x over previous
//
#include <hip/hip_runtime.h>
#include <hip/hip_bf16.h>
#include <stdint.h>

// KipfMLPGNN: B=32, N=64, D=128, H=256, L=3.
// v25 = v24 minus the harmful unroll-2 (R22: VGPR 152, occ 10%):
// isolates the occupancy lever on the v16 champion:
//  - E16: E' materialized once per layer as fp16 (k_esum, L2-resident);
//    T-GEMM A-frags read E16 directly -> no Els LDS stage -> LDS 36KB ->
//    4 blocks/CU eligible (v16: 53KB -> 2).
//  - edge r-loop unroll 1 (v16's proven register profile, ~100 VGPR).

#define NB 32
#define NN 64
#define DD 128
#define HH 256

typedef __attribute__((ext_vector_type(4))) float f32x4;
typedef __attribute__((ext_vector_type(8))) _Float16 f16x8;

__device__ __forceinline__ uint64_t cvt4h(f32x4 v) {
  union { _Float16 h[4]; uint64_t u; } x;
  x.h[0] = (_Float16)v[0]; x.h[1] = (_Float16)v[1];
  x.h[2] = (_Float16)v[2]; x.h[3] = (_Float16)v[3];
  return x.u;
}

// Fused setup: gather E0 (256 blk) | W1/W2 -> fp16 (192 blk)
__global__ __launch_bounds__(256) void k_setup(const int* __restrict__ x,
                                               const float* __restrict__ table,
                                               float* __restrict__ E0,
                                               const float* __restrict__ W1_0,
                                               const float* __restrict__ W1_1,
                                               const float* __restrict__ W2_0,
                                               const float* __restrict__ W2_1,
                                               _Float16* __restrict__ W1fp,
                                               _Float16* __restrict__ W2fp) {
  int bid = blockIdx.x, t = threadIdx.x;
  if (bid < 256) {
    int i = bid * 256 + t;
    int node = i >> 5;
    ((f32x4*)E0)[i] = ((const f32x4*)table)[(size_t)x[node] * 32 + (i & 31)];
  } else {
    int tid = (bid - 256) * 256 + t;     // 49152 f32x4 chunks
    const float* src; uint64_t* dst; int off;
    if (tid < 32768) {
      src = (tid < 16384) ? W1_0 : W1_1;
      off = tid & 16383;
      dst = (uint64_t*)W1fp + (tid >> 14) * 16384 + off;
    } else {
      int t2 = tid - 32768;
      src = (t2 < 8192) ? W2_0 : W2_1;
      off = t2 & 8191;
      dst = (uint64_t*)W2fp + (t2 >> 13) * 8192 + off;
    }
    *dst = cvt4h(((const f32x4*)src)[off]);
  }
}

// E16[node][128] f16 = E0 [+ spA slices] [+ spB slices]   (65536 chunks)
template <int NSP>
__global__ __launch_bounds__(256) void k_esum(const float* __restrict__ E0,
                                              const float* __restrict__ spA,
                                              const float* __restrict__ spB,
                                              _Float16* __restrict__ E16) {
  int i = blockIdx.x * 256 + threadIdx.x;
  f32x4 v = ((const f32x4*)E0)[i];
  if (NSP >= 1) {
#pragma unroll
    for (int s = 0; s < 2; ++s) v += ((const f32x4*)spA)[s * 65536 + i];
  }
  if (NSP >= 2) {
#pragma unroll
    for (int s = 0; s < 2; ++s) v += ((const f32x4*)spB)[s * 65536 + i];
  }
  ((uint64_t*)E16)[i] = cvt4h(v);
}

// k_fused<NR>: grid (NR==8 ? 8 : 1, 32, 2) = (rg, b, p). 256 thr / 4 waves.
template <int NR>
__global__ __launch_bounds__(256) void k_fused(
    const _Float16* __restrict__ E16,
    float* __restrict__ spOut,
    const _Float16* __restrict__ W1fp,
    const _Float16* __restrict__ W2fp,
    const float* __restrict__ b1_0, const float* __restrict__ b1_1,
    const float* __restrict__ b2_0, const float* __restrict__ b2_1,
    const int* __restrict__ arcs) {
  __shared__ char lds[36864];
  char* Tsl = lds;            // [64 c][512 B]  Ts f16, swizzled
  char* Trl = lds + 32768;    // [8 r][512 B]   Tr f16 (+b1), swizzled

  int t = threadIdx.x;
  int rg = blockIdx.x, b = blockIdx.y, p = blockIdx.z;
  int rbase = rg * NR;
  int lane = t & 63, w = t >> 6, col = lane & 15, khi = lane >> 4;
  const f32x4 z4 = {0.f, 0.f, 0.f, 0.f};
  const _Float16* Eb = E16 + (size_t)b * NN * DD;

  // ---- phase 1: T-GEMM (A-frags direct from global E16, L2-hit) ----
  const _Float16* Wq = W1fp + p * 65536;     // [256 h][256 in]
  const float* b1p = p ? b1_1 : b1_0;

#pragma unroll
  for (int nth = 0; nth < 2; ++nth) {        // Ts: 64 c x 32 h per pass
    f16x8 bfr[2][4];
#pragma unroll
    for (int nt = 0; nt < 2; ++nt) {
      int h = w * 64 + nth * 32 + nt * 16 + col;
#pragma unroll
      for (int ks = 0; ks < 4; ++ks)
        bfr[nt][ks] = *(const f16x8*)(Wq + h * 256 + ks * 32 + khi * 8);
    }
    f32x4 tacc[4][2];
#pragma unroll
    for (int mt = 0; mt < 4; ++mt) { tacc[mt][0] = z4; tacc[mt][1] = z4; }
#pragma unroll
    for (int ks = 0; ks < 4; ++ks) {
      f16x8 a[4];
#pragma unroll
      for (int mt = 0; mt < 4; ++mt) {
        int node = mt * 16 + col;
        a[mt] = *(const f16x8*)(Eb + node * DD + ks * 32 + khi * 8);
      }
#pragma unroll
      for (int mt = 0; mt < 4; ++mt) {
        tacc[mt][0] = __builtin_amdgcn_mfma_f32_16x16x32_f16(a[mt], bfr[0][ks],
                                                             tacc[mt][0], 0, 0, 0);
        tacc[mt][1] = __builtin_amdgcn_mfma_f32_16x16x32_f16(a[mt], bfr[1][ks],
                                                             tacc[mt][1], 0, 0, 0);
      }
    }
#pragma unroll
    for (int mt = 0; mt < 4; ++mt)
#pragma unroll
      for (int nt = 0; nt < 2; ++nt) {
        int h = w * 64 + nth * 32 + nt * 16 + col;
#pragma unroll
        for (int j = 0; j < 4; ++j) {
          int c = mt * 16 + khi * 4 + j;
          *(_Float16*)(Tsl + c * 512 + ((h * 2) ^ ((c & 7) << 4))) =
              (_Float16)tacc[mt][nt][j];
        }
      }
  }
  {  // Tr: one 16-node group; keep 8 rows selected by sel
    int mt_t = (NR == 1) ? 0 : (rg >> 1);
    int sel = (NR == 1) ? 0 : (rg & 1);
#pragma unroll
    for (int nth = 0; nth < 2; ++nth) {
      f16x8 bfr[2][4];
#pragma unroll
      for (int nt = 0; nt < 2; ++nt) {
        int h = w * 64 + nth * 32 + nt * 16 + col;
#pragma unroll
        for (int ks = 0; ks < 4; ++ks)
          bfr[nt][ks] = *(const f16x8*)(Wq + h * 256 + 128 + ks * 32 + khi * 8);
      }
      f32x4 tacc[2] = {z4, z4};
#pragma unroll
      for (int ks = 0; ks < 4; ++ks) {
        int node = mt_t * 16 + col;
        f16x8 a = *(const f16x8*)(Eb + node * DD + ks * 32 + khi * 8);
        tacc[0] = __builtin_amdgcn_mfma_f32_16x16x32_f16(a, bfr[0][ks], tacc[0], 0, 0, 0);
        tacc[1] = __builtin_amdgcn_mfma_f32_16x16x32_f16(a, bfr[1][ks], tacc[1], 0, 0, 0);
      }
      if ((khi >> 1) == sel) {
#pragma unroll
        for (int nt = 0; nt < 2; ++nt) {
          int h = w * 64 + nth * 32 + nt * 16 + col;
          float bb = b1p[h];
#pragma unroll
          for (int j = 0; j < 4; ++j) {
            int lr = (khi & 1) * 4 + j;
            *(_Float16*)(Trl + lr * 512 + ((h * 2) ^ ((lr & 7) << 4))) =
                (_Float16)(tacc[nt][j] + bb);
          }
        }
      }
    }
  }
  __syncthreads();

  // ---- phase 2: edge loop; wave w owns d [w*32, w*32+32) ----
  int d0 = w * 32 + col;
  const _Float16* W2p = W2fp + p * 32768;
  f16x8 bv[2][8];
#pragma unroll
  for (int nt = 0; nt < 2; ++nt)
#pragma unroll
    for (int ks = 0; ks < 8; ++ks)
      bv[nt][ks] = *(const f16x8*)(W2p + (d0 + nt * 16) * 256 + ks * 32 + khi * 8);
  const float* b2p = p ? b2_1 : b2_0;
  float b2v[2] = {b2p[d0], b2p[d0 + 16]};

#pragma unroll 1
  for (int r = 0; r < NR; ++r) {
    f32x4 acc[4][2];
#pragma unroll
    for (int mt = 0; mt < 4; ++mt) { acc[mt][0] = z4; acc[mt][1] = z4; }
#pragma unroll
    for (int ks = 0; ks < 8; ++ks) {
      f16x8 trv = *(const f16x8*)(Trl + r * 512 +
                                  ((ks * 64 + khi * 16) ^ ((r & 7) << 4)));
#pragma unroll
      for (int mt = 0; mt < 4; ++mt) {
        int c = mt * 16 + col;
        f16x8 ts = *(const f16x8*)(Tsl + c * 512 +
                                   ((ks * 64 + khi * 16) ^ ((c & 7) << 4)));
        f16x8 zv = {};
        f16x8 a = __builtin_elementwise_max(ts + trv, zv);
        acc[mt][0] = __builtin_amdgcn_mfma_f32_16x16x32_f16(a, bv[0][ks],
                                                            acc[mt][0], 0, 0, 0);
        acc[mt][1] = __builtin_amdgcn_mfma_f32_16x16x32_f16(a, bv[1][ks],
                                                            acc[mt][1], 0, 0, 0);
      }
    }
    int rr = rbase + r;
    const int* arow = arcs + ((size_t)(b * NN + rr)) * NN;
    float s0 = 0.f, s1 = 0.f;
#pragma unroll
    for (int mt = 0; mt < 4; ++mt) {
      const int4 av = *(const int4*)(arow + mt * 16 + khi * 4);
#pragma unroll
      for (int j = 0; j < 4; ++j) {
        int ai = (j == 0) ? av.x : (j == 1) ? av.y : (j == 2) ? av.z : av.w;
        float wgt = p ? (float)ai : 1.0f - (float)ai;
        s0 = fmaf(wgt, fmaxf(acc[mt][0][j] + b2v[0], 0.f), s0);
        s1 = fmaf(wgt, fmaxf(acc[mt][1][j] + b2v[1], 0.f), s1);
      }
    }
    s0 += __shfl_xor(s0, 16); s0 += __shfl_xor(s0, 32);
    s1 += __shfl_xor(s1, 16); s1 += __shfl_xor(s1, 32);
    if (khi == 0) {
      if (NR == 1) {
        float* o = spOut + (size_t)(p * NB + b) * DD;
        o[d0] = s0; o[d0 + 16] = s1;
      } else {
        float* o = spOut + ((size_t)(p * NB + b) * NN + rr) * DD;
        o[d0] = s0; o[d0 + 16] = s1;
      }
    }
  }
}

// out[b][d] = E0[b][0][d] + SpA[0..1][b][0][d] + SpB[0..1][b][0][d] + SpC[0..1][b][d]
__global__ __launch_bounds__(256) void k_out(const float* __restrict__ E0,
                                             const float* __restrict__ spA,
                                             const float* __restrict__ spB,
                                             const float* __restrict__ spC,
                                             float* __restrict__ out) {
  int i = blockIdx.x * 256 + threadIdx.x;      // 4096
  int b = i >> 7, d = i & 127;
  float acc = E0[(size_t)b * NN * DD + d];
  acc += spA[(size_t)b * NN * DD + d] + spA[(size_t)(NB + b) * NN * DD + d];
  acc += spB[(size_t)b * NN * DD + d] + spB[(size_t)(NB + b) * NN * DD + d];
  acc += spC[(size_t)b * DD + d] + spC[(size_t)(NB + b) * DD + d];
  out[i] = acc;
}

extern "C" void kernel_launch(void* const* d_in, const int* in_sizes, int n_in,
                              void* d_out, int out_size, void* d_ws, size_t ws_size,
                              hipStream_t stream) {
  const int* x       = (const int*)d_in[0];
  const int* arcs    = (const int*)d_in[1];
  const float* table = (const float*)d_in[3];
  const float* W1_0  = (const float*)d_in[4];
  const float* b1_0  = (const float*)d_in[5];
  const float* W2_0  = (const float*)d_in[6];
  const float* b2_0  = (const float*)d_in[7];
  const float* W1_1  = (const float*)d_in[8];
  const float* b1_1  = (const float*)d_in[9];
  const float* W2_1  = (const float*)d_in[10];
  const float* b2_1  = (const float*)d_in[11];
  float* out = (float*)d_out;

  char* ws = (char*)d_ws;
  float* E0        = (float*)ws;                                   // 1 MB
  _Float16* W1fp   = (_Float16*)(ws + (1u << 20));                 // 256 KB
  _Float16* W2fp   = (_Float16*)(ws + (1u << 20) + (256u << 10));  // 128 KB
  _Float16* E16    = (_Float16*)(ws + (1u << 20) + (384u << 10));  // 512 KB
  float* SpA       = (float*)(ws + (2u << 20));                    // 2 MB
  float* SpB       = (float*)(ws + (4u << 20));                    // 2 MB
  float* SpC       = (float*)(ws + (6u << 20));                    // 32 KB

  k_setup<<<448, 256, 0, stream>>>(x, table, E0, W1_0, W1_1, W2_0, W2_1,
                                   W1fp, W2fp);
  k_esum<0><<<256, 256, 0, stream>>>(E0, E0, E0, E16);
  k_fused<8><<<dim3(8, 32, 2), 256, 0, stream>>>(
      E16, SpA, W1fp, W2fp, b1_0, b1_1, b2_0, b2_1, arcs);
  k_esum<1><<<256, 256, 0, stream>>>(E0, SpA, E0, E16);
  k_fused<8><<<dim3(8, 32, 2), 256, 0, stream>>>(
      E16, SpB, W1fp, W2fp, b1_0, b1_1, b2_0, b2_1, arcs);
  k_esum<2><<<256, 256, 0, stream>>>(E0, SpA, SpB, E16);
  k_fused<1><<<dim3(1, 32, 2), 256, 0, stream>>>(
      E16, SpC, W1fp, W2fp, b1_0, b1_1, b2_0, b2_1, arcs);
  k_out<<<16, 256, 0, stream>>>(E0, SpA, SpB, SpC, out);
}

// Round 24
// 102.406 us; speedup vs baseline: 1.1575x; 1.1184x over previous
//
#include <hip/hip_runtime.h>
#include <hip/hip_bf16.h>
#include <stdint.h>

// KipfMLPGNN: B=32, N=64, D=128, H=256, L=3.
// v26 = v16 (champion, 102us) with phase-1 staging fed from E16:
//  - k_esum materializes E' per layer as fp16 (0.5MB, L2-resident).
//  - k_fused stages Els from E16 (16KB fp16 single stream, plain uint64
//    copies) instead of folding E0 + 4 Sp f32 streams in-kernel
//    (80KB/block, R20 showed this traffic class costs 10-18us/dispatch).
//  - T-GEMM A-frags from LDS (v16's proven 84-VGPR profile; R23 showed
//    direct-global A-frags inflate VGPR to 148 via load hoisting).
// Everything downstream of staging is byte-identical to v16.

#define NB 32
#define NN 64
#define DD 128
#define HH 256

typedef __attribute__((ext_vector_type(4))) float f32x4;
typedef __attribute__((ext_vector_type(8))) _Float16 f16x8;

__device__ __forceinline__ uint64_t cvt4h(f32x4 v) {
  union { _Float16 h[4]; uint64_t u; } x;
  x.h[0] = (_Float16)v[0]; x.h[1] = (_Float16)v[1];
  x.h[2] = (_Float16)v[2]; x.h[3] = (_Float16)v[3];
  return x.u;
}

// Fused setup: gather E0 (256 blk) | W1/W2 -> fp16 (192 blk)
__global__ __launch_bounds__(256) void k_setup(const int* __restrict__ x,
                                               const float* __restrict__ table,
                                               float* __restrict__ E0,
                                               const float* __restrict__ W1_0,
                                               const float* __restrict__ W1_1,
                                               const float* __restrict__ W2_0,
                                               const float* __restrict__ W2_1,
                                               _Float16* __restrict__ W1fp,
                                               _Float16* __restrict__ W2fp) {
  int bid = blockIdx.x, t = threadIdx.x;
  if (bid < 256) {
    int i = bid * 256 + t;
    int node = i >> 5;
    ((f32x4*)E0)[i] = ((const f32x4*)table)[(size_t)x[node] * 32 + (i & 31)];
  } else {
    int tid = (bid - 256) * 256 + t;     // 49152 f32x4 chunks
    const float* src; uint64_t* dst; int off;
    if (tid < 32768) {
      src = (tid < 16384) ? W1_0 : W1_1;
      off = tid & 16383;
      dst = (uint64_t*)W1fp + (tid >> 14) * 16384 + off;
    } else {
      int t2 = tid - 32768;
      src = (t2 < 8192) ? W2_0 : W2_1;
      off = t2 & 8191;
      dst = (uint64_t*)W2fp + (t2 >> 13) * 8192 + off;
    }
    *dst = cvt4h(((const f32x4*)src)[off]);
  }
}

// E16[node][128] f16 = E0 [+ spA slices] [+ spB slices]   (65536 chunks)
template <int NSP>
__global__ __launch_bounds__(256) void k_esum(const float* __restrict__ E0,
                                              const float* __restrict__ spA,
                                              const float* __restrict__ spB,
                                              _Float16* __restrict__ E16) {
  int i = blockIdx.x * 256 + threadIdx.x;
  f32x4 v = ((const f32x4*)E0)[i];
  if (NSP >= 1) {
#pragma unroll
    for (int s = 0; s < 2; ++s) v += ((const f32x4*)spA)[s * 65536 + i];
  }
  if (NSP >= 2) {
#pragma unroll
    for (int s = 0; s < 2; ++s) v += ((const f32x4*)spB)[s * 65536 + i];
  }
  ((uint64_t*)E16)[i] = cvt4h(v);
}

// k_fused<NR>: grid (NR==8 ? 8 : 1, 32, 2) = (rg, b, p). 256 thr / 4 waves.
template <int NR>
__global__ __launch_bounds__(256) void k_fused(
    const _Float16* __restrict__ E16,
    float* __restrict__ spOut,
    const _Float16* __restrict__ W1fp,
    const _Float16* __restrict__ W2fp,
    const float* __restrict__ b1_0, const float* __restrict__ b1_1,
    const float* __restrict__ b2_0, const float* __restrict__ b2_1,
    const int* __restrict__ arcs) {
  __shared__ char lds[53248];
  char* Els = lds;            // [64 node][256 B]  E' f16, swizzled
  char* Tsl = lds + 16384;    // [64 c][512 B]     Ts f16, swizzled
  char* Trl = lds + 49152;    // [8 r][512 B]      Tr f16 (+b1), swizzled

  int t = threadIdx.x;
  int rg = blockIdx.x, b = blockIdx.y, p = blockIdx.z;
  int rbase = rg * NR;
  int lane = t & 63, w = t >> 6, col = lane & 15, khi = lane >> 4;
  const f32x4 z4 = {0.f, 0.f, 0.f, 0.f};

  // ---- phase 1: stage E' (fp16, single stream) -> Els swizzled ----
  {
    const uint64_t* src = (const uint64_t*)(E16 + (size_t)b * NN * DD);
#pragma unroll
    for (int ii = 0; ii < 8; ++ii) {
      int idx = ii * 256 + t;          // 2048 chunks: node=idx>>5, ck=idx&31
      int node = idx >> 5, ck = idx & 31;
      *(uint64_t*)(Els + node * 256 + ((ck * 8) ^ ((node & 7) << 4))) = src[idx];
    }
  }
  __syncthreads();

  // ---- phase 2: T-GEMM (A-frags from LDS) ----
  const _Float16* Wq = W1fp + p * 65536;     // [256 h][256 in]
  const float* b1p = p ? b1_1 : b1_0;

#pragma unroll
  for (int nth = 0; nth < 2; ++nth) {        // Ts: two N-halves per wave
    f16x8 bfr[2][4];
#pragma unroll
    for (int nt = 0; nt < 2; ++nt) {
      int h = w * 64 + nth * 32 + nt * 16 + col;
#pragma unroll
      for (int ks = 0; ks < 4; ++ks)
        bfr[nt][ks] = *(const f16x8*)(Wq + h * 256 + ks * 32 + khi * 8);
    }
    f32x4 tacc[4][2];
#pragma unroll
    for (int mt = 0; mt < 4; ++mt) { tacc[mt][0] = z4; tacc[mt][1] = z4; }
#pragma unroll
    for (int ks = 0; ks < 4; ++ks) {
      f16x8 a[4];
#pragma unroll
      for (int mt = 0; mt < 4; ++mt) {
        int c = mt * 16 + col;
        a[mt] = *(const f16x8*)(Els + c * 256 + ((ks * 64 + khi * 16) ^ ((c & 7) << 4)));
      }
#pragma unroll
      for (int mt = 0; mt < 4; ++mt) {
        tacc[mt][0] = __builtin_amdgcn_mfma_f32_16x16x32_f16(a[mt], bfr[0][ks],
                                                             tacc[mt][0], 0, 0, 0);
        tacc[mt][1] = __builtin_amdgcn_mfma_f32_16x16x32_f16(a[mt], bfr[1][ks],
                                                             tacc[mt][1], 0, 0, 0);
      }
    }
#pragma unroll
    for (int mt = 0; mt < 4; ++mt)
#pragma unroll
      for (int nt = 0; nt < 2; ++nt) {
        int h = w * 64 + nth * 32 + nt * 16 + col;
#pragma unroll
        for (int j = 0; j < 4; ++j) {
          int c = mt * 16 + khi * 4 + j;
          *(_Float16*)(Tsl + c * 512 + ((h * 2) ^ ((c & 7) << 4))) =
              (_Float16)tacc[mt][nt][j];
        }
      }
  }
  {  // Tr: one mt-tile covering rows rbase..rbase+7
    int mt_t = (NR == 1) ? 0 : (rg >> 1);
    int sel = (NR == 1) ? 0 : (rg & 1);
#pragma unroll
    for (int nth = 0; nth < 2; ++nth) {
      f16x8 bfr[2][4];
#pragma unroll
      for (int nt = 0; nt < 2; ++nt) {
        int h = w * 64 + nth * 32 + nt * 16 + col;
#pragma unroll
        for (int ks = 0; ks < 4; ++ks)
          bfr[nt][ks] = *(const f16x8*)(Wq + h * 256 + 128 + ks * 32 + khi * 8);
      }
      f32x4 tacc[2] = {z4, z4};
#pragma unroll
      for (int ks = 0; ks < 4; ++ks) {
        int c = mt_t * 16 + col;
        f16x8 a = *(const f16x8*)(Els + c * 256 +
                                  ((ks * 64 + khi * 16) ^ ((c & 7) << 4)));
        tacc[0] = __builtin_amdgcn_mfma_f32_16x16x32_f16(a, bfr[0][ks], tacc[0], 0, 0, 0);
        tacc[1] = __builtin_amdgcn_mfma_f32_16x16x32_f16(a, bfr[1][ks], tacc[1], 0, 0, 0);
      }
      if ((khi >> 1) == sel) {
#pragma unroll
        for (int nt = 0; nt < 2; ++nt) {
          int h = w * 64 + nth * 32 + nt * 16 + col;
          float bb = b1p[h];
#pragma unroll
          for (int j = 0; j < 4; ++j) {
            int lr = (khi & 1) * 4 + j;
            *(_Float16*)(Trl + lr * 512 + ((h * 2) ^ ((lr & 7) << 4))) =
                (_Float16)(tacc[nt][j] + bb);
          }
        }
      }
    }
  }
  __syncthreads();

  // ---- phase 3: edge loop; wave w owns d [w*32, w*32+32) ----
  int d0 = w * 32 + col;
  const _Float16* W2p = W2fp + p * 32768;
  f16x8 bv[2][8];
#pragma unroll
  for (int nt = 0; nt < 2; ++nt)
#pragma unroll
    for (int ks = 0; ks < 8; ++ks)
      bv[nt][ks] = *(const f16x8*)(W2p + (d0 + nt * 16) * 256 + ks * 32 + khi * 8);
  const float* b2p = p ? b2_1 : b2_0;
  float b2v[2] = {b2p[d0], b2p[d0 + 16]};

#pragma unroll 1
  for (int r = 0; r < NR; ++r) {
    f32x4 acc[4][2];
#pragma unroll
    for (int mt = 0; mt < 4; ++mt) { acc[mt][0] = z4; acc[mt][1] = z4; }
#pragma unroll
    for (int ks = 0; ks < 8; ++ks) {
      f16x8 trv = *(const f16x8*)(Trl + r * 512 +
                                  ((ks * 64 + khi * 16) ^ ((r & 7) << 4)));
#pragma unroll
      for (int mt = 0; mt < 4; ++mt) {
        int c = mt * 16 + col;
        f16x8 ts = *(const f16x8*)(Tsl + c * 512 +
                                   ((ks * 64 + khi * 16) ^ ((c & 7) << 4)));
        f16x8 zv = {};
        f16x8 a = __builtin_elementwise_max(ts + trv, zv);
        acc[mt][0] = __builtin_amdgcn_mfma_f32_16x16x32_f16(a, bv[0][ks],
                                                            acc[mt][0], 0, 0, 0);
        acc[mt][1] = __builtin_amdgcn_mfma_f32_16x16x32_f16(a, bv[1][ks],
                                                            acc[mt][1], 0, 0, 0);
      }
    }
    int rr = rbase + r;
    const int* arow = arcs + ((size_t)(b * NN + rr)) * NN;
    float s0 = 0.f, s1 = 0.f;
#pragma unroll
    for (int mt = 0; mt < 4; ++mt) {
      const int4 av = *(const int4*)(arow + mt * 16 + khi * 4);
#pragma unroll
      for (int j = 0; j < 4; ++j) {
        int ai = (j == 0) ? av.x : (j == 1) ? av.y : (j == 2) ? av.z : av.w;
        float wgt = p ? (float)ai : 1.0f - (float)ai;
        s0 = fmaf(wgt, fmaxf(acc[mt][0][j] + b2v[0], 0.f), s0);
        s1 = fmaf(wgt, fmaxf(acc[mt][1][j] + b2v[1], 0.f), s1);
      }
    }
    s0 += __shfl_xor(s0, 16); s0 += __shfl_xor(s0, 32);
    s1 += __shfl_xor(s1, 16); s1 += __shfl_xor(s1, 32);
    if (khi == 0) {
      if (NR == 1) {
        float* o = spOut + (size_t)(p * NB + b) * DD;
        o[d0] = s0; o[d0 + 16] = s1;
      } else {
        float* o = spOut + ((size_t)(p * NB + b) * NN + rr) * DD;
        o[d0] = s0; o[d0 + 16] = s1;
      }
    }
  }
}

// out[b][d] = E0[b][0][d] + SpA[0..1][b][0][d] + SpB[0..1][b][0][d] + SpC[0..1][b][d]
__global__ __launch_bounds__(256) void k_out(const float* __restrict__ E0,
                                             const float* __restrict__ spA,
                                             const float* __restrict__ spB,
                                             const float* __restrict__ spC,
                                             float* __restrict__ out) {
  int i = blockIdx.x * 256 + threadIdx.x;      // 4096
  int b = i >> 7, d = i & 127;
  float acc = E0[(size_t)b * NN * DD + d];
  acc += spA[(size_t)b * NN * DD + d] + spA[(size_t)(NB + b) * NN * DD + d];
  acc += spB[(size_t)b * NN * DD + d] + spB[(size_t)(NB + b) * NN * DD + d];
  acc += spC[(size_t)b * DD + d] + spC[(size_t)(NB + b) * DD + d];
  out[i] = acc;
}

extern "C" void kernel_launch(void* const* d_in, const int* in_sizes, int n_in,
                              void* d_out, int out_size, void* d_ws, size_t ws_size,
                              hipStream_t stream) {
  const int* x       = (const int*)d_in[0];
  const int* arcs    = (const int*)d_in[1];
  const float* table = (const float*)d_in[3];
  const float* W1_0  = (const float*)d_in[4];
  const float* b1_0  = (const float*)d_in[5];
  const float* W2_0  = (const float*)d_in[6];
  const float* b2_0  = (const float*)d_in[7];
  const float* W1_1  = (const float*)d_in[8];
  const float* b1_1  = (const float*)d_in[9];
  const float* W2_1  = (const float*)d_in[10];
  const float* b2_1  = (const float*)d_in[11];
  float* out = (float*)d_out;

  char* ws = (char*)d_ws;
  float* E0        = (float*)ws;                                   // 1 MB
  _Float16* W1fp   = (_Float16*)(ws + (1u << 20));                 // 256 KB
  _Float16* W2fp   = (_Float16*)(ws + (1u << 20) + (256u << 10));  // 128 KB
  _Float16* E16    = (_Float16*)(ws + (1u << 20) + (384u << 10));  // 512 KB
  float* SpA       = (float*)(ws + (2u << 20));                    // 2 MB
  float* SpB       = (float*)(ws + (4u << 20));                    // 2 MB
  float* SpC       = (float*)(ws + (6u << 20));                    // 32 KB

  k_setup<<<448, 256, 0, stream>>>(x, table, E0, W1_0, W1_1, W2_0, W2_1,
                                   W1fp, W2fp);
  k_esum<0><<<256, 256, 0, stream>>>(E0, E0, E0, E16);
  k_fused<8><<<dim3(8, 32, 2), 256, 0, stream>>>(
      E16, SpA, W1fp, W2fp, b1_0, b1_1, b2_0, b2_1, arcs);
  k_esum<1><<<256, 256, 0, stream>>>(E0, SpA, E0, E16);
  k_fused<8><<<dim3(8, 32, 2), 256, 0, stream>>>(
      E16, SpB, W1fp, W2fp, b1_0, b1_1, b2_0, b2_1, arcs);
  k_esum<2><<<256, 256, 0, stream>>>(E0, SpA, SpB, E16);
  k_fused<1><<<dim3(1, 32, 2), 256, 0, stream>>>(
      E16, SpC, W1fp, W2fp, b1_0, b1_1, b2_0, b2_1, arcs);
  k_out<<<16, 256, 0, stream>>>(E0, SpA, SpB, SpC, out);
}